// Round 17
// baseline (95.004 us; speedup 1.0000x reference)
//
#include <hip/hip_runtime.h>
#include <hip/hip_bf16.h>
#include <math.h>

#define NH 8
#define HD 48
#define C_DIM 384
#define C3 1152
#define SCALE_F 0.14433756729740643f

typedef unsigned short ushort_t;
typedef __attribute__((ext_vector_type(8))) short short8;
typedef __attribute__((ext_vector_type(4))) float f32x4;

static __device__ __forceinline__ ushort_t bf16u(float f) {
    __hip_bfloat16 b = __float2bfloat16(f);
    return *(ushort_t*)&b;
}

// ---------------------------------------------------------------------------
// fp32 -> bf16 (hi, lo) elementwise split:  x ~= hi + lo, each bf16.
// ---------------------------------------------------------------------------
__global__ __launch_bounds__(256) void split_bf16_kernel(const float* __restrict__ in,
                                                         ushort_t* __restrict__ hi,
                                                         ushort_t* __restrict__ lo,
                                                         int n4)
{
    const int i = blockIdx.x * 256 + threadIdx.x;
    if (i >= n4) return;
    const float4 v = ((const float4*)in)[i];
    const float f[4] = {v.x, v.y, v.z, v.w};
    ushort_t hb[4], lb[4];
    #pragma unroll
    for (int j = 0; j < 4; ++j) {
        __hip_bfloat16 h = __float2bfloat16(f[j]);
        __hip_bfloat16 l = __float2bfloat16(f[j] - __bfloat162float(h));
        hb[j] = *(ushort_t*)&h;
        lb[j] = *(ushort_t*)&l;
    }
    *(ushort4*)(hi + i * 4) = make_ushort4(hb[0], hb[1], hb[2], hb[3]);
    *(ushort4*)(lo + i * 4) = make_ushort4(lb[0], lb[1], lb[2], lb[3]);
}

// ---------------------------------------------------------------------------
// fp32 W[K][N] -> transposed bf16 splits WT_hi[N][K], WT_lo[N][K].
// ---------------------------------------------------------------------------
__global__ __launch_bounds__(256) void split_wT_kernel(const float* __restrict__ w,
                                                       ushort_t* __restrict__ hiT,
                                                       ushort_t* __restrict__ loT,
                                                       int K, int N)
{
    const int idx = blockIdx.x * 256 + threadIdx.x;
    if (idx >= K * N) return;
    const int k = idx / N;
    const int n = idx - k * N;
    const float v = w[idx];
    __hip_bfloat16 h = __float2bfloat16(v);
    __hip_bfloat16 l = __float2bfloat16(v - __bfloat162float(h));
    hiT[n * K + k] = *(ushort_t*)&h;
    loT[n * K + k] = *(ushort_t*)&l;
}

// ---------------------------------------------------------------------------
// Split-precision MFMA GEMM, 128x64 tile, 256 thr (proj / fallback producer).
// ---------------------------------------------------------------------------
__global__ __launch_bounds__(256) void gemm_mfma3(const ushort_t* __restrict__ Ah,
                                                  const ushort_t* __restrict__ Al,
                                                  const ushort_t* __restrict__ BhT,
                                                  const ushort_t* __restrict__ BlT,
                                                  const float* __restrict__ bias,
                                                  float* __restrict__ C,
                                                  int N, int K)
{
    __shared__ ushort_t sAh[128 * 40];
    __shared__ ushort_t sAl[128 * 40];
    __shared__ ushort_t sBh[64 * 40];
    __shared__ ushort_t sBl[64 * 40];

    const int tid = threadIdx.x;
    const int bm = blockIdx.x * 128;
    const int bn = blockIdx.y * 64;

    const int rowA = tid >> 2;
    const int slotA = (tid & 3) * 8;
    const int rowB = tid >> 2;
    const int slotB = (tid & 3) * 8;

    const ushort_t* gAh0 = Ah + (size_t)(bm + rowA) * K + slotA;
    const ushort_t* gAh1 = Ah + (size_t)(bm + rowA + 64) * K + slotA;
    const ushort_t* gAl0 = Al + (size_t)(bm + rowA) * K + slotA;
    const ushort_t* gAl1 = Al + (size_t)(bm + rowA + 64) * K + slotA;
    const ushort_t* gBh  = BhT + (size_t)(bn + rowB) * K + slotB;
    const ushort_t* gBl  = BlT + (size_t)(bn + rowB) * K + slotB;

    const int lane = tid & 63;
    const int wid = tid >> 6;
    const int wm = wid >> 1;
    const int wn = wid & 1;
    const int fr = lane & 15;
    const int kb = lane >> 4;
    const int aoff = (wm * 64 + fr) * 40 + kb * 8;
    const int boff = (wn * 32 + fr) * 40 + kb * 8;

    f32x4 acc[4][2] = {};

    for (int k0 = 0; k0 < K; k0 += 32) {
        const short8 va0 = *(const short8*)(gAh0 + k0);
        const short8 va1 = *(const short8*)(gAh1 + k0);
        const short8 vl0 = *(const short8*)(gAl0 + k0);
        const short8 vl1 = *(const short8*)(gAl1 + k0);
        const short8 vb0 = *(const short8*)(gBh + k0);
        const short8 vb1 = *(const short8*)(gBl + k0);
        *(short8*)&sAh[rowA * 40 + slotA]        = va0;
        *(short8*)&sAh[(rowA + 64) * 40 + slotA] = va1;
        *(short8*)&sAl[rowA * 40 + slotA]        = vl0;
        *(short8*)&sAl[(rowA + 64) * 40 + slotA] = vl1;
        *(short8*)&sBh[rowB * 40 + slotB]        = vb0;
        *(short8*)&sBl[rowB * 40 + slotB]        = vb1;
        __syncthreads();

        short8 ah[4], al[4], bh[2], bl[2];
        #pragma unroll
        for (int m = 0; m < 4; ++m) {
            ah[m] = *(const short8*)&sAh[aoff + m * 16 * 40];
            al[m] = *(const short8*)&sAl[aoff + m * 16 * 40];
        }
        #pragma unroll
        for (int n = 0; n < 2; ++n) {
            bh[n] = *(const short8*)&sBh[boff + n * 16 * 40];
            bl[n] = *(const short8*)&sBl[boff + n * 16 * 40];
        }
        #pragma unroll
        for (int m = 0; m < 4; ++m) {
            #pragma unroll
            for (int n = 0; n < 2; ++n) {
                acc[m][n] = __builtin_amdgcn_mfma_f32_16x16x32_bf16(ah[m], bh[n], acc[m][n], 0, 0, 0);
                acc[m][n] = __builtin_amdgcn_mfma_f32_16x16x32_bf16(ah[m], bl[n], acc[m][n], 0, 0, 0);
                acc[m][n] = __builtin_amdgcn_mfma_f32_16x16x32_bf16(al[m], bh[n], acc[m][n], 0, 0, 0);
            }
        }
        __syncthreads();
    }

    #pragma unroll
    for (int n = 0; n < 2; ++n) {
        const int col = bn + wn * 32 + n * 16 + fr;
        const float bv = bias ? bias[col] : 0.f;
        #pragma unroll
        for (int m = 0; m < 4; ++m) {
            const int r0 = bm + wm * 64 + m * 16 + kb * 4;
            #pragma unroll
            for (int r = 0; r < 4; ++r) {
                C[(size_t)(r0 + r) * N + col] = acc[m][n][r] + bv;
            }
        }
    }
}

// ---------------------------------------------------------------------------
// Split-precision MFMA GEMM, WIDE: 128x128 tile, 512 thr, 8 waves (2x4).
// Same frag math/epilogue formulas as gemm_mfma3; LDS 40KB -> 4 blocks/CU;
// halves A/B re-staging, 2x MFMA per barrier pair.  Used for the QKV GEMM.
// ---------------------------------------------------------------------------
__global__ __launch_bounds__(512) void gemm_mfma3w(const ushort_t* __restrict__ Ah,
                                                   const ushort_t* __restrict__ Al,
                                                   const ushort_t* __restrict__ BhT,
                                                   const ushort_t* __restrict__ BlT,
                                                   float* __restrict__ C,
                                                   int N, int K)
{
    __shared__ ushort_t sAh[128 * 40];
    __shared__ ushort_t sAl[128 * 40];
    __shared__ ushort_t sBh[128 * 40];
    __shared__ ushort_t sBl[128 * 40];

    const int tid = threadIdx.x;
    const int bm = blockIdx.x * 128;
    const int bn = blockIdx.y * 128;

    const int rowA = tid >> 2;            // 0..127
    const int slotA = (tid & 3) * 8;

    const ushort_t* gAh = Ah + (size_t)(bm + rowA) * K + slotA;
    const ushort_t* gAl = Al + (size_t)(bm + rowA) * K + slotA;
    const ushort_t* gBh = BhT + (size_t)(bn + rowA) * K + slotA;
    const ushort_t* gBl = BlT + (size_t)(bn + rowA) * K + slotA;

    const int lane = tid & 63;
    const int wid = tid >> 6;             // 0..7
    const int wm = wid >> 2;              // 0..1
    const int wn = wid & 3;               // 0..3
    const int fr = lane & 15;
    const int kb = lane >> 4;
    const int aoff = (wm * 64 + fr) * 40 + kb * 8;
    const int boff = (wn * 32 + fr) * 40 + kb * 8;

    f32x4 acc[4][2] = {};

    for (int k0 = 0; k0 < K; k0 += 32) {
        const short8 va = *(const short8*)(gAh + k0);
        const short8 vl = *(const short8*)(gAl + k0);
        const short8 vb = *(const short8*)(gBh + k0);
        const short8 vc = *(const short8*)(gBl + k0);
        *(short8*)&sAh[rowA * 40 + slotA] = va;
        *(short8*)&sAl[rowA * 40 + slotA] = vl;
        *(short8*)&sBh[rowA * 40 + slotA] = vb;
        *(short8*)&sBl[rowA * 40 + slotA] = vc;
        __syncthreads();

        short8 ah[4], al[4], bh[2], bl[2];
        #pragma unroll
        for (int m = 0; m < 4; ++m) {
            ah[m] = *(const short8*)&sAh[aoff + m * 16 * 40];
            al[m] = *(const short8*)&sAl[aoff + m * 16 * 40];
        }
        #pragma unroll
        for (int n = 0; n < 2; ++n) {
            bh[n] = *(const short8*)&sBh[boff + n * 16 * 40];
            bl[n] = *(const short8*)&sBl[boff + n * 16 * 40];
        }
        #pragma unroll
        for (int m = 0; m < 4; ++m) {
            #pragma unroll
            for (int n = 0; n < 2; ++n) {
                acc[m][n] = __builtin_amdgcn_mfma_f32_16x16x32_bf16(ah[m], bh[n], acc[m][n], 0, 0, 0);
                acc[m][n] = __builtin_amdgcn_mfma_f32_16x16x32_bf16(ah[m], bl[n], acc[m][n], 0, 0, 0);
                acc[m][n] = __builtin_amdgcn_mfma_f32_16x16x32_bf16(al[m], bh[n], acc[m][n], 0, 0, 0);
            }
        }
        __syncthreads();
    }

    #pragma unroll
    for (int n = 0; n < 2; ++n) {
        const int col = bn + wn * 32 + n * 16 + fr;
        #pragma unroll
        for (int m = 0; m < 4; ++m) {
            const int r0 = bm + wm * 64 + m * 16 + kb * 4;
            #pragma unroll
            for (int r = 0; r < 4; ++r) {
                C[(size_t)(r0 + r) * N + col] = acc[m][n][r];
            }
        }
    }
}

// ---------------------------------------------------------------------------
// fp32 fallback GEMM (only if ws too small for MFMA path).
// ---------------------------------------------------------------------------
__global__ __launch_bounds__(256) void gemm64(const float* __restrict__ A,
                                              const float* __restrict__ B,
                                              const float* __restrict__ bias,
                                              float* __restrict__ C,
                                              int M, int N, int K)
{
    __shared__ float As[64][17];
    __shared__ float Bs[16][64];

    const int tid = threadIdx.x;
    const int tx = tid & 15;
    const int ty = tid >> 4;
    const int bm = blockIdx.x * 64;
    const int bn = blockIdx.y * 64;
    const int arow = tid >> 2;
    const int acol = (tid & 3) << 2;
    const int brow = tid >> 4;
    const int bcol = (tid & 15) << 2;

    float acc[4][4] = {};

    for (int k0 = 0; k0 < K; k0 += 16) {
        const float4 a4 = *(const float4*)(A + (size_t)(bm + arow) * K + k0 + acol);
        const float4 b4 = *(const float4*)(B + (size_t)(k0 + brow) * N + bn + bcol);
        As[arow][acol + 0] = a4.x; As[arow][acol + 1] = a4.y;
        As[arow][acol + 2] = a4.z; As[arow][acol + 3] = a4.w;
        *(float4*)&Bs[brow][bcol] = b4;
        __syncthreads();
        #pragma unroll
        for (int kk = 0; kk < 16; ++kk) {
            const float a0 = As[ty * 4 + 0][kk];
            const float a1 = As[ty * 4 + 1][kk];
            const float a2 = As[ty * 4 + 2][kk];
            const float a3 = As[ty * 4 + 3][kk];
            const float4 b = *(const float4*)&Bs[kk][tx * 4];
            acc[0][0] = fmaf(a0, b.x, acc[0][0]); acc[0][1] = fmaf(a0, b.y, acc[0][1]);
            acc[0][2] = fmaf(a0, b.z, acc[0][2]); acc[0][3] = fmaf(a0, b.w, acc[0][3]);
            acc[1][0] = fmaf(a1, b.x, acc[1][0]); acc[1][1] = fmaf(a1, b.y, acc[1][1]);
            acc[1][2] = fmaf(a1, b.z, acc[1][2]); acc[1][3] = fmaf(a1, b.w, acc[1][3]);
            acc[2][0] = fmaf(a2, b.x, acc[2][0]); acc[2][1] = fmaf(a2, b.y, acc[2][1]);
            acc[2][2] = fmaf(a2, b.z, acc[2][2]); acc[2][3] = fmaf(a2, b.w, acc[2][3]);
            acc[3][0] = fmaf(a3, b.x, acc[3][0]); acc[3][1] = fmaf(a3, b.y, acc[3][1]);
            acc[3][2] = fmaf(a3, b.z, acc[3][2]); acc[3][3] = fmaf(a3, b.w, acc[3][3]);
        }
        __syncthreads();
    }

    float4 bb = {0.f, 0.f, 0.f, 0.f};
    if (bias) bb = *(const float4*)(bias + bn + tx * 4);
    #pragma unroll
    for (int i = 0; i < 4; ++i) {
        float4 o;
        o.x = acc[i][0] + bb.x; o.y = acc[i][1] + bb.y;
        o.z = acc[i][2] + bb.z; o.w = acc[i][3] + bb.w;
        *(float4*)(C + (size_t)(bm + ty * 4 + i) * N + bn + tx * 4) = o;
    }
}

// ---------------------------------------------------------------------------
// MFMA local attention v5 = v4 + T14 async-STAGE split for V:
// phase 2 issues V float2 loads into REGISTERS (static unroll), score MFMAs
// run while loads fly; cvt+LDS-store lands in phase 3 with softmax||zero-P.
// Arithmetic bitwise identical to v4/v2b.
// ---------------------------------------------------------------------------
#define KP_SHORTS 18432   // K: 280 rows*64 = 17920 staged + 512 pad; P: 7*32*72 = 16128
#define PROW 72
__global__ __launch_bounds__(512) void local_attn_mfma5(const float* __restrict__ qkv,
                                                        ushort_t* __restrict__ outHi,
                                                        ushort_t* __restrict__ outLo)
{
    __shared__ ushort_t sKP[KP_SHORTS];     // 36864 B
    __shared__ ushort_t sV[13504];          // 27008 B (13440 staged + 64 pad)
    __shared__ ushort_t sQ[2048];           //  4096 B (32 q x 64 d, swizzled)
    __shared__ float    sS[32 * 57];        //  7296 B (57 coprime 32 -> bank-clean)

    const int tid = threadIdx.x;
    const int b = blockIdx.x;
    const int t = b >> 8, h = (b >> 3) & 31, head = b & 7;

    // ---- zero ONLY the frag-overrun pads (NaN-safety; 0 x NaN = NaN) ----
    if (tid < 288) {
        if (tid < 256) ((unsigned int*)(sKP + 17920))[tid] = 0u;
        else           ((unsigned int*)(sV + 13440))[tid - 256] = 0u;
    }

    // ---- phase 1: stage Q + K only (float2 loads, packed stores) ----
    #pragma unroll
    for (int it = 0; it < 2; ++it) {
        const int i = tid + it * 512;
        const int q = i >> 5, d = (i & 31) * 2;
        float2 v = make_float2(0.f, 0.f);
        if (d < 48)
            v = *(const float2*)(qkv + (size_t)((t << 10) + (h << 5) + q) * C3 + head * HD + d);
        const unsigned int pk = (unsigned int)bf16u(v.x * SCALE_F) | ((unsigned int)bf16u(v.y * SCALE_F) << 16);
        *(unsigned int*)&sQ[q * 64 + (d ^ ((q & 7) << 3))] = pk;
    }
    #pragma unroll
    for (int r = 0; r < 7; ++r) {
        const int hk = h + r - 3;
        const bool rowok = (unsigned)hk < 32u;
        const size_t rk = (size_t)((t << 10) + (hk << 5)) * C3 + C_DIM + head * HD;
        for (int i = tid; i < 1280; i += 512) {
            const int slot = i >> 5, d = (i & 31) * 2;
            const int c = slot - 3;
            float2 v = make_float2(0.f, 0.f);
            if (rowok && (unsigned)c < 32u && d < 48)
                v = *(const float2*)(qkv + rk + (size_t)c * C3 + d);
            const unsigned int pk = (unsigned int)bf16u(v.x) | ((unsigned int)bf16u(v.y) << 16);
            *(unsigned int*)&sKP[(r * 40 + slot) * 64 + (d ^ ((slot & 7) << 3))] = pk;
        }
    }
    __syncthreads();

    const int wv = tid >> 6, l = tid & 63, lr = l & 15, lc = l >> 4;

    // ---- phase 2: ISSUE V loads to regs, then scores (loads fly under MFMA) ----
    float2 vreg[7][2];
    #pragma unroll
    for (int r = 0; r < 7; ++r) {
        const int hk = h + r - 3;
        const bool rowok = (unsigned)hk < 32u;
        const size_t rv = (size_t)((t << 10) + (hk << 5)) * C3 + 2 * C_DIM + head * HD;
        #pragma unroll
        for (int it = 0; it < 2; ++it) {
            const int i = tid + it * 512;
            float2 v = make_float2(0.f, 0.f);
            if (i < 960) {
                const int slot = i / 24;
                const int d = (i - slot * 24) * 2;
                const int c = slot - 3;
                if (rowok && (unsigned)c < 32u)
                    v = *(const float2*)(qkv + rv + (size_t)c * C3 + d);
            }
            vreg[r][it] = v;
        }
    }
    {
        short8 aq[2][2];
        #pragma unroll
        for (int fm = 0; fm < 2; ++fm) {
            const int q = fm * 16 + lr;
            aq[fm][0] = *(const short8*)&sQ[q * 64 + ((lc * 8) ^ ((q & 7) << 3))];
            aq[fm][1] = *(const short8*)&sQ[q * 64 + ((lc * 8 + 32) ^ ((q & 7) << 3))];
        }
        for (int u = wv; u < 21; u += 8) {
            const int r = u / 3, fn = u - r * 3;
            const int slot = fn * 16 + lr;
            const short8 b0 = *(const short8*)&sKP[(r * 40 + slot) * 64 + ((lc * 8) ^ ((slot & 7) << 3))];
            const short8 b1 = *(const short8*)&sKP[(r * 40 + slot) * 64 + ((lc * 8 + 32) ^ ((slot & 7) << 3))];
            f32x4 acc0 = {}, acc1 = {};
            acc0 = __builtin_amdgcn_mfma_f32_16x16x32_bf16(aq[0][0], b0, acc0, 0, 0, 0);
            acc0 = __builtin_amdgcn_mfma_f32_16x16x32_bf16(aq[0][1], b1, acc0, 0, 0, 0);
            acc1 = __builtin_amdgcn_mfma_f32_16x16x32_bf16(aq[1][0], b0, acc1, 0, 0, 0);
            acc1 = __builtin_amdgcn_mfma_f32_16x16x32_bf16(aq[1][1], b1, acc1, 0, 0, 0);
            // banded scatter: keep C elem (q, slot) iff 0 <= slot - q <= 6
            #pragma unroll
            for (int reg = 0; reg < 4; ++reg) {
                const int q0 = lc * 4 + reg;
                const int dx0 = slot - q0;
                if (dx0 >= 0 && dx0 < 7) sS[q0 * 57 + r * 7 + dx0] = acc0[reg];
                const int q1 = 16 + lc * 4 + reg;
                const int dx1 = slot - q1;
                if (dx1 >= 0 && dx1 < 7) sS[q1 * 57 + r * 7 + dx1] = acc1[reg];
            }
        }
    }
    __syncthreads();

    // ---- phase 3: V cvt+store (all) + softmax (0..31) || zero-P (32..511) ----
    #pragma unroll
    for (int r = 0; r < 7; ++r) {
        #pragma unroll
        for (int it = 0; it < 2; ++it) {
            const int i = tid + it * 512;
            if (i < 960) {
                const int slot = i / 24;
                const int d = (i - slot * 24) * 2;
                sV[(r * 48 + d) * 40 + slot]     = bf16u(vreg[r][it].x);
                sV[(r * 48 + d + 1) * 40 + slot] = bf16u(vreg[r][it].y);
            }
        }
    }
    if (tid < 32) {
        const int q = tid;
        float sv[49];
        #pragma unroll
        for (int j = 0; j < 49; ++j) sv[j] = sS[q * 57 + j];
        float mx = sv[0];
        #pragma unroll
        for (int j = 1; j < 49; ++j) mx = fmaxf(mx, sv[j]);
        float sum = 0.f;
        #pragma unroll
        for (int j = 0; j < 49; ++j) { sv[j] = __expf(sv[j] - mx); sum += sv[j]; }
        const float inv = 1.f / sum;   // zero-padded keys in denominator (ref semantics)
        #pragma unroll
        for (int j = 0; j < 49; ++j) {
            const int r = j / 7, dx = j - (j / 7) * 7;
            sKP[(r * 32 + q) * PROW + q + dx] = bf16u(sv[j] * inv);
        }
    } else {
        for (int i = tid - 32; i < 7 * 32 * PROW; i += 480) {
            const int row = i / PROW;
            const int col = i - row * PROW;
            const int q = row & 31;
            if ((unsigned)(col - q) >= 7u)     // skip softmax band
                sKP[i] = 0;
        }
    }
    __syncthreads();

    // ---- phase 4: PV (waves 0..5 own (fm, fn) tiles) + fused hi/lo split ----
    if (wv < 6) {
        const int fm = (wv >= 3) ? 1 : 0;
        const int fn = wv - fm * 3;
        const int q = fm * 16 + lr;
        const int dim = fn * 16 + lr;
        f32x4 acc = {};
        #pragma unroll
        for (int r = 0; r < 7; ++r) {
            const short8 a0 = *(const short8*)&sKP[(r * 32 + q) * PROW + lc * 8];
            const short8 a1 = *(const short8*)&sKP[(r * 32 + q) * PROW + lc * 8 + 32];
            const short8 b0 = *(const short8*)&sV[(r * 48 + dim) * 40 + lc * 8];
            const short8 b1 = *(const short8*)&sV[(r * 48 + dim) * 40 + lc * 8 + 32];
            acc = __builtin_amdgcn_mfma_f32_16x16x32_bf16(a0, b0, acc, 0, 0, 0);
            acc = __builtin_amdgcn_mfma_f32_16x16x32_bf16(a1, b1, acc, 0, 0, 0);
        }
        #pragma unroll
        for (int reg = 0; reg < 4; ++reg) {
            const int qq = fm * 16 + lc * 4 + reg;
            const int n = (t << 10) | (h << 5) | qq;
            const float o = acc[reg];
            __hip_bfloat16 hb = __float2bfloat16(o);
            __hip_bfloat16 lb = __float2bfloat16(o - __bfloat162float(hb));
            const size_t ob = (size_t)n * C_DIM + head * HD + dim;
            outHi[ob] = *(ushort_t*)&hb;
            outLo[ob] = *(ushort_t*)&lb;
        }
    }
}

// ---------------------------------------------------------------------------
// fp32 fallback attention (only if ws too small for MFMA path).
// ---------------------------------------------------------------------------
__global__ __launch_bounds__(256) void local_attn16(const float* __restrict__ qkv,
                                                    float* __restrict__ out)
{
    const int tid = threadIdx.x;
    const int dlane = tid & 15;
    const int gid = blockIdx.x * 16 + (tid >> 4);
    const int head = gid & 7;
    const int n = gid >> 3;
    const int t = n >> 10;
    const int h = (n >> 5) & 31;
    const int w = n & 31;
    const float scale = SCALE_F;

    const float* qp = qkv + (size_t)n * C3 + head * HD;
    const float q0 = qp[dlane];
    const float q1 = qp[dlane + 16];
    const float q2 = qp[dlane + 32];

    const size_t base_k = (size_t)(C_DIM + head * HD);
    const size_t base_v = (size_t)(2 * C_DIM + head * HD);

    float s[49];
    #pragma unroll
    for (int p = 0; p < 49; ++p) {
        const int dy = p / 7, dx = p % 7;
        const int hk = h + dy - 3;
        const int wk = w + dx - 3;
        float sc = 0.f;
        if ((unsigned)hk < 32u && (unsigned)wk < 32u) {
            const int nk = (t << 10) | (hk << 5) | wk;
            const float* kp = qkv + (size_t)nk * C3 + base_k;
            float acc = q0 * kp[dlane];
            acc = fmaf(q1, kp[dlane + 16], acc);
            acc = fmaf(q2, kp[dlane + 32], acc);
            acc += __shfl_xor(acc, 1, 16);
            acc += __shfl_xor(acc, 2, 16);
            acc += __shfl_xor(acc, 4, 16);
            acc += __shfl_xor(acc, 8, 16);
            sc = acc * scale;
        }
        s[p] = sc;
    }

    float m = s[0];
    #pragma unroll
    for (int p = 1; p < 49; ++p) m = fmaxf(m, s[p]);
    float sum = 0.f;
    #pragma unroll
    for (int p = 0; p < 49; ++p) { s[p] = __expf(s[p] - m); sum += s[p]; }
    const float inv = 1.f / sum;

    float o0 = 0.f, o1 = 0.f, o2 = 0.f;
    #pragma unroll
    for (int p = 0; p < 49; ++p) {
        const int dy = p / 7, dx = p % 7;
        const int hk = h + dy - 3;
        const int wk = w + dx - 3;
        if ((unsigned)hk < 32u && (unsigned)wk < 32u) {
            const float wgt = s[p] * inv;
            const int nk = (t << 10) | (hk << 5) | wk;
            const float* vp = qkv + (size_t)nk * C3 + base_v;
            o0 = fmaf(wgt, vp[dlane],      o0);
            o1 = fmaf(wgt, vp[dlane + 16], o1);
            o2 = fmaf(wgt, vp[dlane + 32], o2);
        }
    }

    float* op = out + (size_t)n * C_DIM + head * HD;
    op[dlane]      = o0;
    op[dlane + 16] = o1;
    op[dlane + 32] = o2;
}

extern "C" void kernel_launch(void* const* d_in, const int* in_sizes, int n_in,
                              void* d_out, int out_size, void* d_ws, size_t ws_size,
                              hipStream_t stream)
{
    const float* x      = (const float*)d_in[0];
    const float* w_qkv  = (const float*)d_in[1];
    const float* w_proj = (const float*)d_in[2];
    const float* b_proj = (const float*)d_in[3];

    const int M = 4096;
    dim3 blk(256);

    // ws layout (bytes):
    //   qkv fp32   [4096x1152] @ 0         (18,874,368)
    //   att fp32   [4096x384]  @ 18874368  ( 6,291,456)  (fallback only)
    //   Ah  bf16   [4096x384]  @ 25165824  ( 3,145,728)
    //   Al  bf16   [4096x384]  @ 28311552  ( 3,145,728)
    //   BhT bf16   [1152x384]  @ 31457280  (   884,736)
    //   BlT bf16   [1152x384]  @ 32342016  (   884,736)
    const size_t NEED = 33226752;

    unsigned char* ws = (unsigned char*)d_ws;
    float* qkv = (float*)ws;
    float* att = (float*)(ws + 18874368);

    if (ws_size >= NEED) {
        ushort_t* Ah  = (ushort_t*)(ws + 25165824);
        ushort_t* Al  = (ushort_t*)(ws + 28311552);
        ushort_t* BhT = (ushort_t*)(ws + 31457280);
        ushort_t* BlT = (ushort_t*)(ws + 32342016);

        split_bf16_kernel<<<dim3(1536), blk, 0, stream>>>(x, Ah, Al, M * C_DIM / 4);
        split_wT_kernel<<<dim3((C_DIM * C3 + 255) / 256), blk, 0, stream>>>(w_qkv, BhT, BlT, C_DIM, C3);
        // QKV GEMM on the wide 128x128 tile (288 blocks, 4 blocks/CU)
        gemm_mfma3w<<<dim3(M / 128, C3 / 128), dim3(512), 0, stream>>>(Ah, Al, BhT, BlT, qkv, C3, C_DIM);

        // MFMA attention v5: T14 V-split; writes bf16 hi/lo split directly
        local_attn_mfma5<<<dim3(1024), dim3(512), 0, stream>>>(qkv, Ah, Al);

        split_wT_kernel<<<dim3((C_DIM * C_DIM + 255) / 256), blk, 0, stream>>>(w_proj, BhT, BlT, C_DIM, C_DIM);
        gemm_mfma3<<<dim3(M / 128, C_DIM / 64), blk, 0, stream>>>(Ah, Al, BhT, BlT, b_proj, (float*)d_out, C_DIM, C_DIM);
    } else {
        gemm64<<<dim3(M / 64, C3 / 64), blk, 0, stream>>>(x, w_qkv, nullptr, qkv, M, C3, C_DIM);
        local_attn16<<<dim3(2048), blk, 0, stream>>>(qkv, att);
        gemm64<<<dim3(M / 64, C_DIM / 64), blk, 0, stream>>>(att, w_proj, b_proj, (float*)d_out, M, C_DIM, C_DIM);
    }
}

// Round 19
// 91.835 us; speedup vs baseline: 1.0345x; 1.0345x over previous
//
#include <hip/hip_runtime.h>
#include <hip/hip_bf16.h>
#include <math.h>

#define NH 8
#define HD 48
#define C_DIM 384
#define C3 1152
#define SCALE_F 0.14433756729740643f

typedef unsigned short ushort_t;
typedef __attribute__((ext_vector_type(8))) short short8;
typedef __attribute__((ext_vector_type(4))) float f32x4;

static __device__ __forceinline__ ushort_t bf16u(float f) {
    __hip_bfloat16 b = __float2bfloat16(f);
    return *(ushort_t*)&b;
}

// ---------------------------------------------------------------------------
// fp32 -> bf16 (hi, lo) elementwise split:  x ~= hi + lo, each bf16.
// ---------------------------------------------------------------------------
__global__ __launch_bounds__(256) void split_bf16_kernel(const float* __restrict__ in,
                                                         ushort_t* __restrict__ hi,
                                                         ushort_t* __restrict__ lo,
                                                         int n4)
{
    const int i = blockIdx.x * 256 + threadIdx.x;
    if (i >= n4) return;
    const float4 v = ((const float4*)in)[i];
    const float f[4] = {v.x, v.y, v.z, v.w};
    ushort_t hb[4], lb[4];
    #pragma unroll
    for (int j = 0; j < 4; ++j) {
        __hip_bfloat16 h = __float2bfloat16(f[j]);
        __hip_bfloat16 l = __float2bfloat16(f[j] - __bfloat162float(h));
        hb[j] = *(ushort_t*)&h;
        lb[j] = *(ushort_t*)&l;
    }
    *(ushort4*)(hi + i * 4) = make_ushort4(hb[0], hb[1], hb[2], hb[3]);
    *(ushort4*)(lo + i * 4) = make_ushort4(lb[0], lb[1], lb[2], lb[3]);
}

// ---------------------------------------------------------------------------
// fp32 W[K][N] -> transposed bf16 splits WT_hi[N][K], WT_lo[N][K].
// ---------------------------------------------------------------------------
__global__ __launch_bounds__(256) void split_wT_kernel(const float* __restrict__ w,
                                                       ushort_t* __restrict__ hiT,
                                                       ushort_t* __restrict__ loT,
                                                       int K, int N)
{
    const int idx = blockIdx.x * 256 + threadIdx.x;
    if (idx >= K * N) return;
    const int k = idx / N;
    const int n = idx - k * N;
    const float v = w[idx];
    __hip_bfloat16 h = __float2bfloat16(v);
    __hip_bfloat16 l = __float2bfloat16(v - __bfloat162float(h));
    hiT[n * K + k] = *(ushort_t*)&h;
    loT[n * K + k] = *(ushort_t*)&l;
}

// ---------------------------------------------------------------------------
// Split-precision MFMA GEMM: C ~= AhBh + AhBl + AlBh (fp32-equivalent).
// Tile 128x64, BK=32, 4 waves, 4x2 frags of v_mfma_f32_16x16x32_bf16.
// 576 blocks @ N=1152 -> ~2.25 blocks/CU queued, ~5 concurrent by LDS: good
// load balance (the 128x128/512thr variant had a 288-block tail — r17 regression).
// ---------------------------------------------------------------------------
__global__ __launch_bounds__(256) void gemm_mfma3(const ushort_t* __restrict__ Ah,
                                                  const ushort_t* __restrict__ Al,
                                                  const ushort_t* __restrict__ BhT,
                                                  const ushort_t* __restrict__ BlT,
                                                  const float* __restrict__ bias,
                                                  float* __restrict__ C,
                                                  int N, int K)
{
    __shared__ ushort_t sAh[128 * 40];
    __shared__ ushort_t sAl[128 * 40];
    __shared__ ushort_t sBh[64 * 40];
    __shared__ ushort_t sBl[64 * 40];

    const int tid = threadIdx.x;
    const int bm = blockIdx.x * 128;
    const int bn = blockIdx.y * 64;

    const int rowA = tid >> 2;
    const int slotA = (tid & 3) * 8;
    const int rowB = tid >> 2;
    const int slotB = (tid & 3) * 8;

    const ushort_t* gAh0 = Ah + (size_t)(bm + rowA) * K + slotA;
    const ushort_t* gAh1 = Ah + (size_t)(bm + rowA + 64) * K + slotA;
    const ushort_t* gAl0 = Al + (size_t)(bm + rowA) * K + slotA;
    const ushort_t* gAl1 = Al + (size_t)(bm + rowA + 64) * K + slotA;
    const ushort_t* gBh  = BhT + (size_t)(bn + rowB) * K + slotB;
    const ushort_t* gBl  = BlT + (size_t)(bn + rowB) * K + slotB;

    const int lane = tid & 63;
    const int wid = tid >> 6;
    const int wm = wid >> 1;
    const int wn = wid & 1;
    const int fr = lane & 15;
    const int kb = lane >> 4;
    const int aoff = (wm * 64 + fr) * 40 + kb * 8;
    const int boff = (wn * 32 + fr) * 40 + kb * 8;

    f32x4 acc[4][2] = {};

    for (int k0 = 0; k0 < K; k0 += 32) {
        const short8 va0 = *(const short8*)(gAh0 + k0);
        const short8 va1 = *(const short8*)(gAh1 + k0);
        const short8 vl0 = *(const short8*)(gAl0 + k0);
        const short8 vl1 = *(const short8*)(gAl1 + k0);
        const short8 vb0 = *(const short8*)(gBh + k0);
        const short8 vb1 = *(const short8*)(gBl + k0);
        *(short8*)&sAh[rowA * 40 + slotA]        = va0;
        *(short8*)&sAh[(rowA + 64) * 40 + slotA] = va1;
        *(short8*)&sAl[rowA * 40 + slotA]        = vl0;
        *(short8*)&sAl[(rowA + 64) * 40 + slotA] = vl1;
        *(short8*)&sBh[rowB * 40 + slotB]        = vb0;
        *(short8*)&sBl[rowB * 40 + slotB]        = vb1;
        __syncthreads();

        short8 ah[4], al[4], bh[2], bl[2];
        #pragma unroll
        for (int m = 0; m < 4; ++m) {
            ah[m] = *(const short8*)&sAh[aoff + m * 16 * 40];
            al[m] = *(const short8*)&sAl[aoff + m * 16 * 40];
        }
        #pragma unroll
        for (int n = 0; n < 2; ++n) {
            bh[n] = *(const short8*)&sBh[boff + n * 16 * 40];
            bl[n] = *(const short8*)&sBl[boff + n * 16 * 40];
        }
        #pragma unroll
        for (int m = 0; m < 4; ++m) {
            #pragma unroll
            for (int n = 0; n < 2; ++n) {
                acc[m][n] = __builtin_amdgcn_mfma_f32_16x16x32_bf16(ah[m], bh[n], acc[m][n], 0, 0, 0);
                acc[m][n] = __builtin_amdgcn_mfma_f32_16x16x32_bf16(ah[m], bl[n], acc[m][n], 0, 0, 0);
                acc[m][n] = __builtin_amdgcn_mfma_f32_16x16x32_bf16(al[m], bh[n], acc[m][n], 0, 0, 0);
            }
        }
        __syncthreads();
    }

    #pragma unroll
    for (int n = 0; n < 2; ++n) {
        const int col = bn + wn * 32 + n * 16 + fr;
        const float bv = bias ? bias[col] : 0.f;
        #pragma unroll
        for (int m = 0; m < 4; ++m) {
            const int r0 = bm + wm * 64 + m * 16 + kb * 4;
            #pragma unroll
            for (int r = 0; r < 4; ++r) {
                C[(size_t)(r0 + r) * N + col] = acc[m][n][r] + bv;
            }
        }
    }
}

// ---------------------------------------------------------------------------
// fp32 fallback GEMM (only if ws too small for MFMA path).
// ---------------------------------------------------------------------------
__global__ __launch_bounds__(256) void gemm64(const float* __restrict__ A,
                                              const float* __restrict__ B,
                                              const float* __restrict__ bias,
                                              float* __restrict__ C,
                                              int M, int N, int K)
{
    __shared__ float As[64][17];
    __shared__ float Bs[16][64];

    const int tid = threadIdx.x;
    const int tx = tid & 15;
    const int ty = tid >> 4;
    const int bm = blockIdx.x * 64;
    const int bn = blockIdx.y * 64;
    const int arow = tid >> 2;
    const int acol = (tid & 3) << 2;
    const int brow = tid >> 4;
    const int bcol = (tid & 15) << 2;

    float acc[4][4] = {};

    for (int k0 = 0; k0 < K; k0 += 16) {
        const float4 a4 = *(const float4*)(A + (size_t)(bm + arow) * K + k0 + acol);
        const float4 b4 = *(const float4*)(B + (size_t)(k0 + brow) * N + bn + bcol);
        As[arow][acol + 0] = a4.x; As[arow][acol + 1] = a4.y;
        As[arow][acol + 2] = a4.z; As[arow][acol + 3] = a4.w;
        *(float4*)&Bs[brow][bcol] = b4;
        __syncthreads();
        #pragma unroll
        for (int kk = 0; kk < 16; ++kk) {
            const float a0 = As[ty * 4 + 0][kk];
            const float a1 = As[ty * 4 + 1][kk];
            const float a2 = As[ty * 4 + 2][kk];
            const float a3 = As[ty * 4 + 3][kk];
            const float4 b = *(const float4*)&Bs[kk][tx * 4];
            acc[0][0] = fmaf(a0, b.x, acc[0][0]); acc[0][1] = fmaf(a0, b.y, acc[0][1]);
            acc[0][2] = fmaf(a0, b.z, acc[0][2]); acc[0][3] = fmaf(a0, b.w, acc[0][3]);
            acc[1][0] = fmaf(a1, b.x, acc[1][0]); acc[1][1] = fmaf(a1, b.y, acc[1][1]);
            acc[1][2] = fmaf(a1, b.z, acc[1][2]); acc[1][3] = fmaf(a1, b.w, acc[1][3]);
            acc[2][0] = fmaf(a2, b.x, acc[2][0]); acc[2][1] = fmaf(a2, b.y, acc[2][1]);
            acc[2][2] = fmaf(a2, b.z, acc[2][2]); acc[2][3] = fmaf(a2, b.w, acc[2][3]);
            acc[3][0] = fmaf(a3, b.x, acc[3][0]); acc[3][1] = fmaf(a3, b.y, acc[3][1]);
            acc[3][2] = fmaf(a3, b.z, acc[3][2]); acc[3][3] = fmaf(a3, b.w, acc[3][3]);
        }
        __syncthreads();
    }

    float4 bb = {0.f, 0.f, 0.f, 0.f};
    if (bias) bb = *(const float4*)(bias + bn + tx * 4);
    #pragma unroll
    for (int i = 0; i < 4; ++i) {
        float4 o;
        o.x = acc[i][0] + bb.x; o.y = acc[i][1] + bb.y;
        o.z = acc[i][2] + bb.z; o.w = acc[i][3] + bb.w;
        *(float4*)(C + (size_t)(bm + ty * 4 + i) * N + bn + tx * 4) = o;
    }
}

// ---------------------------------------------------------------------------
// MFMA local attention v5 = v4 + T14 async-STAGE split for V:
// phase 2 issues V float2 loads into REGISTERS (static unroll), score MFMAs
// run while loads fly; cvt+LDS-store lands in phase 3 with softmax||zero-P.
// Arithmetic bitwise identical to v4/v2b.
// ---------------------------------------------------------------------------
#define KP_SHORTS 18432   // K: 280 rows*64 = 17920 staged + 512 pad; P: 7*32*72 = 16128
#define PROW 72
__global__ __launch_bounds__(512) void local_attn_mfma5(const float* __restrict__ qkv,
                                                        ushort_t* __restrict__ outHi,
                                                        ushort_t* __restrict__ outLo)
{
    __shared__ ushort_t sKP[KP_SHORTS];     // 36864 B
    __shared__ ushort_t sV[13504];          // 27008 B (13440 staged + 64 pad)
    __shared__ ushort_t sQ[2048];           //  4096 B (32 q x 64 d, swizzled)
    __shared__ float    sS[32 * 57];        //  7296 B (57 coprime 32 -> bank-clean)

    const int tid = threadIdx.x;
    const int b = blockIdx.x;
    const int t = b >> 8, h = (b >> 3) & 31, head = b & 7;

    // ---- zero ONLY the frag-overrun pads (NaN-safety; 0 x NaN = NaN) ----
    if (tid < 288) {
        if (tid < 256) ((unsigned int*)(sKP + 17920))[tid] = 0u;
        else           ((unsigned int*)(sV + 13440))[tid - 256] = 0u;
    }

    // ---- phase 1: stage Q + K only (float2 loads, packed stores) ----
    #pragma unroll
    for (int it = 0; it < 2; ++it) {
        const int i = tid + it * 512;
        const int q = i >> 5, d = (i & 31) * 2;
        float2 v = make_float2(0.f, 0.f);
        if (d < 48)
            v = *(const float2*)(qkv + (size_t)((t << 10) + (h << 5) + q) * C3 + head * HD + d);
        const unsigned int pk = (unsigned int)bf16u(v.x * SCALE_F) | ((unsigned int)bf16u(v.y * SCALE_F) << 16);
        *(unsigned int*)&sQ[q * 64 + (d ^ ((q & 7) << 3))] = pk;
    }
    #pragma unroll
    for (int r = 0; r < 7; ++r) {
        const int hk = h + r - 3;
        const bool rowok = (unsigned)hk < 32u;
        const size_t rk = (size_t)((t << 10) + (hk << 5)) * C3 + C_DIM + head * HD;
        for (int i = tid; i < 1280; i += 512) {
            const int slot = i >> 5, d = (i & 31) * 2;
            const int c = slot - 3;
            float2 v = make_float2(0.f, 0.f);
            if (rowok && (unsigned)c < 32u && d < 48)
                v = *(const float2*)(qkv + rk + (size_t)c * C3 + d);
            const unsigned int pk = (unsigned int)bf16u(v.x) | ((unsigned int)bf16u(v.y) << 16);
            *(unsigned int*)&sKP[(r * 40 + slot) * 64 + (d ^ ((slot & 7) << 3))] = pk;
        }
    }
    __syncthreads();

    const int wv = tid >> 6, l = tid & 63, lr = l & 15, lc = l >> 4;

    // ---- phase 2: ISSUE V loads to regs, then scores (loads fly under MFMA) ----
    float2 vreg[7][2];
    #pragma unroll
    for (int r = 0; r < 7; ++r) {
        const int hk = h + r - 3;
        const bool rowok = (unsigned)hk < 32u;
        const size_t rv = (size_t)((t << 10) + (hk << 5)) * C3 + 2 * C_DIM + head * HD;
        #pragma unroll
        for (int it = 0; it < 2; ++it) {
            const int i = tid + it * 512;
            float2 v = make_float2(0.f, 0.f);
            if (i < 960) {
                const int slot = i / 24;
                const int d = (i - slot * 24) * 2;
                const int c = slot - 3;
                if (rowok && (unsigned)c < 32u)
                    v = *(const float2*)(qkv + rv + (size_t)c * C3 + d);
            }
            vreg[r][it] = v;
        }
    }
    {
        short8 aq[2][2];
        #pragma unroll
        for (int fm = 0; fm < 2; ++fm) {
            const int q = fm * 16 + lr;
            aq[fm][0] = *(const short8*)&sQ[q * 64 + ((lc * 8) ^ ((q & 7) << 3))];
            aq[fm][1] = *(const short8*)&sQ[q * 64 + ((lc * 8 + 32) ^ ((q & 7) << 3))];
        }
        for (int u = wv; u < 21; u += 8) {
            const int r = u / 3, fn = u - r * 3;
            const int slot = fn * 16 + lr;
            const short8 b0 = *(const short8*)&sKP[(r * 40 + slot) * 64 + ((lc * 8) ^ ((slot & 7) << 3))];
            const short8 b1 = *(const short8*)&sKP[(r * 40 + slot) * 64 + ((lc * 8 + 32) ^ ((slot & 7) << 3))];
            f32x4 acc0 = {}, acc1 = {};
            acc0 = __builtin_amdgcn_mfma_f32_16x16x32_bf16(aq[0][0], b0, acc0, 0, 0, 0);
            acc0 = __builtin_amdgcn_mfma_f32_16x16x32_bf16(aq[0][1], b1, acc0, 0, 0, 0);
            acc1 = __builtin_amdgcn_mfma_f32_16x16x32_bf16(aq[1][0], b0, acc1, 0, 0, 0);
            acc1 = __builtin_amdgcn_mfma_f32_16x16x32_bf16(aq[1][1], b1, acc1, 0, 0, 0);
            // banded scatter: keep C elem (q, slot) iff 0 <= slot - q <= 6
            #pragma unroll
            for (int reg = 0; reg < 4; ++reg) {
                const int q0 = lc * 4 + reg;
                const int dx0 = slot - q0;
                if (dx0 >= 0 && dx0 < 7) sS[q0 * 57 + r * 7 + dx0] = acc0[reg];
                const int q1 = 16 + lc * 4 + reg;
                const int dx1 = slot - q1;
                if (dx1 >= 0 && dx1 < 7) sS[q1 * 57 + r * 7 + dx1] = acc1[reg];
            }
        }
    }
    __syncthreads();

    // ---- phase 3: V cvt+store (all) + softmax (0..31) || zero-P (32..511) ----
    #pragma unroll
    for (int r = 0; r < 7; ++r) {
        #pragma unroll
        for (int it = 0; it < 2; ++it) {
            const int i = tid + it * 512;
            if (i < 960) {
                const int slot = i / 24;
                const int d = (i - slot * 24) * 2;
                sV[(r * 48 + d) * 40 + slot]     = bf16u(vreg[r][it].x);
                sV[(r * 48 + d + 1) * 40 + slot] = bf16u(vreg[r][it].y);
            }
        }
    }
    if (tid < 32) {
        const int q = tid;
        float sv[49];
        #pragma unroll
        for (int j = 0; j < 49; ++j) sv[j] = sS[q * 57 + j];
        float mx = sv[0];
        #pragma unroll
        for (int j = 1; j < 49; ++j) mx = fmaxf(mx, sv[j]);
        float sum = 0.f;
        #pragma unroll
        for (int j = 0; j < 49; ++j) { sv[j] = __expf(sv[j] - mx); sum += sv[j]; }
        const float inv = 1.f / sum;   // zero-padded keys in denominator (ref semantics)
        #pragma unroll
        for (int j = 0; j < 49; ++j) {
            const int r = j / 7, dx = j - (j / 7) * 7;
            sKP[(r * 32 + q) * PROW + q + dx] = bf16u(sv[j] * inv);
        }
    } else {
        for (int i = tid - 32; i < 7 * 32 * PROW; i += 480) {
            const int row = i / PROW;
            const int col = i - row * PROW;
            const int q = row & 31;
            if ((unsigned)(col - q) >= 7u)     // skip softmax band
                sKP[i] = 0;
        }
    }
    __syncthreads();

    // ---- phase 4: PV (waves 0..5 own (fm, fn) tiles) + fused hi/lo split ----
    if (wv < 6) {
        const int fm = (wv >= 3) ? 1 : 0;
        const int fn = wv - fm * 3;
        const int q = fm * 16 + lr;
        const int dim = fn * 16 + lr;
        f32x4 acc = {};
        #pragma unroll
        for (int r = 0; r < 7; ++r) {
            const short8 a0 = *(const short8*)&sKP[(r * 32 + q) * PROW + lc * 8];
            const short8 a1 = *(const short8*)&sKP[(r * 32 + q) * PROW + lc * 8 + 32];
            const short8 b0 = *(const short8*)&sV[(r * 48 + dim) * 40 + lc * 8];
            const short8 b1 = *(const short8*)&sV[(r * 48 + dim) * 40 + lc * 8 + 32];
            acc = __builtin_amdgcn_mfma_f32_16x16x32_bf16(a0, b0, acc, 0, 0, 0);
            acc = __builtin_amdgcn_mfma_f32_16x16x32_bf16(a1, b1, acc, 0, 0, 0);
        }
        #pragma unroll
        for (int reg = 0; reg < 4; ++reg) {
            const int qq = fm * 16 + lc * 4 + reg;
            const int n = (t << 10) | (h << 5) | qq;
            const float o = acc[reg];
            __hip_bfloat16 hb = __float2bfloat16(o);
            __hip_bfloat16 lb = __float2bfloat16(o - __bfloat162float(hb));
            const size_t ob = (size_t)n * C_DIM + head * HD + dim;
            outHi[ob] = *(ushort_t*)&hb;
            outLo[ob] = *(ushort_t*)&lb;
        }
    }
}

// ---------------------------------------------------------------------------
// fp32 fallback attention (only if ws too small for MFMA path).
// ---------------------------------------------------------------------------
__global__ __launch_bounds__(256) void local_attn16(const float* __restrict__ qkv,
                                                    float* __restrict__ out)
{
    const int tid = threadIdx.x;
    const int dlane = tid & 15;
    const int gid = blockIdx.x * 16 + (tid >> 4);
    const int head = gid & 7;
    const int n = gid >> 3;
    const int t = n >> 10;
    const int h = (n >> 5) & 31;
    const int w = n & 31;
    const float scale = SCALE_F;

    const float* qp = qkv + (size_t)n * C3 + head * HD;
    const float q0 = qp[dlane];
    const float q1 = qp[dlane + 16];
    const float q2 = qp[dlane + 32];

    const size_t base_k = (size_t)(C_DIM + head * HD);
    const size_t base_v = (size_t)(2 * C_DIM + head * HD);

    float s[49];
    #pragma unroll
    for (int p = 0; p < 49; ++p) {
        const int dy = p / 7, dx = p % 7;
        const int hk = h + dy - 3;
        const int wk = w + dx - 3;
        float sc = 0.f;
        if ((unsigned)hk < 32u && (unsigned)wk < 32u) {
            const int nk = (t << 10) | (hk << 5) | wk;
            const float* kp = qkv + (size_t)nk * C3 + base_k;
            float acc = q0 * kp[dlane];
            acc = fmaf(q1, kp[dlane + 16], acc);
            acc = fmaf(q2, kp[dlane + 32], acc);
            acc += __shfl_xor(acc, 1, 16);
            acc += __shfl_xor(acc, 2, 16);
            acc += __shfl_xor(acc, 4, 16);
            acc += __shfl_xor(acc, 8, 16);
            sc = acc * scale;
        }
        s[p] = sc;
    }

    float m = s[0];
    #pragma unroll
    for (int p = 1; p < 49; ++p) m = fmaxf(m, s[p]);
    float sum = 0.f;
    #pragma unroll
    for (int p = 0; p < 49; ++p) { s[p] = __expf(s[p] - m); sum += s[p]; }
    const float inv = 1.f / sum;

    float o0 = 0.f, o1 = 0.f, o2 = 0.f;
    #pragma unroll
    for (int p = 0; p < 49; ++p) {
        const int dy = p / 7, dx = p % 7;
        const int hk = h + dy - 3;
        const int wk = w + dx - 3;
        if ((unsigned)hk < 32u && (unsigned)wk < 32u) {
            const float wgt = s[p] * inv;
            const int nk = (t << 10) | (hk << 5) | wk;
            const float* vp = qkv + (size_t)nk * C3 + base_v;
            o0 = fmaf(wgt, vp[dlane],      o0);
            o1 = fmaf(wgt, vp[dlane + 16], o1);
            o2 = fmaf(wgt, vp[dlane + 32], o2);
        }
    }

    float* op = out + (size_t)n * C_DIM + head * HD;
    op[dlane]      = o0;
    op[dlane + 16] = o1;
    op[dlane + 32] = o2;
}

extern "C" void kernel_launch(void* const* d_in, const int* in_sizes, int n_in,
                              void* d_out, int out_size, void* d_ws, size_t ws_size,
                              hipStream_t stream)
{
    const float* x      = (const float*)d_in[0];
    const float* w_qkv  = (const float*)d_in[1];
    const float* w_proj = (const float*)d_in[2];
    const float* b_proj = (const float*)d_in[3];

    const int M = 4096;
    dim3 blk(256);

    // ws layout (bytes):
    //   qkv fp32   [4096x1152] @ 0         (18,874,368)
    //   att fp32   [4096x384]  @ 18874368  ( 6,291,456)  (fallback only)
    //   Ah  bf16   [4096x384]  @ 25165824  ( 3,145,728)
    //   Al  bf16   [4096x384]  @ 28311552  ( 3,145,728)
    //   BhT bf16   [1152x384]  @ 31457280  (   884,736)
    //   BlT bf16   [1152x384]  @ 32342016  (   884,736)
    const size_t NEED = 33226752;

    unsigned char* ws = (unsigned char*)d_ws;
    float* qkv = (float*)ws;
    float* att = (float*)(ws + 18874368);

    if (ws_size >= NEED) {
        ushort_t* Ah  = (ushort_t*)(ws + 25165824);
        ushort_t* Al  = (ushort_t*)(ws + 28311552);
        ushort_t* BhT = (ushort_t*)(ws + 31457280);
        ushort_t* BlT = (ushort_t*)(ws + 32342016);

        split_bf16_kernel<<<dim3(1536), blk, 0, stream>>>(x, Ah, Al, M * C_DIM / 4);
        split_wT_kernel<<<dim3((C_DIM * C3 + 255) / 256), blk, 0, stream>>>(w_qkv, BhT, BlT, C_DIM, C3);
        // QKV GEMM: narrow 128x64 tile, 576 blocks (r16-proven; wide tile regressed)
        gemm_mfma3<<<dim3(M / 128, C3 / 64), blk, 0, stream>>>(Ah, Al, BhT, BlT, nullptr, qkv, C3, C_DIM);

        // MFMA attention v5: T14 V-split; writes bf16 hi/lo split directly
        local_attn_mfma5<<<dim3(1024), dim3(512), 0, stream>>>(qkv, Ah, Al);

        split_wT_kernel<<<dim3((C_DIM * C_DIM + 255) / 256), blk, 0, stream>>>(w_proj, BhT, BlT, C_DIM, C_DIM);
        gemm_mfma3<<<dim3(M / 128, C_DIM / 64), blk, 0, stream>>>(Ah, Al, BhT, BlT, b_proj, (float*)d_out, C_DIM, C_DIM);
    } else {
        gemm64<<<dim3(M / 64, C3 / 64), blk, 0, stream>>>(x, w_qkv, nullptr, qkv, M, C3, C_DIM);
        local_attn16<<<dim3(2048), blk, 0, stream>>>(qkv, att);
        gemm64<<<dim3(M / 64, C_DIM / 64), blk, 0, stream>>>(att, w_proj, b_proj, (float*)d_out, M, C_DIM, C_DIM);
    }
}

// Round 22
// 85.412 us; speedup vs baseline: 1.1123x; 1.0752x over previous
//
#include <hip/hip_runtime.h>
#include <hip/hip_bf16.h>
#include <math.h>

#define NH 8
#define HD 48
#define C_DIM 384
#define C3 1152
#define SCALE_F 0.14433756729740643f

typedef unsigned short ushort_t;
typedef __attribute__((ext_vector_type(8))) short short8;
typedef __attribute__((ext_vector_type(4))) float f32x4;

static __device__ __forceinline__ ushort_t bf16u(float f) {
    __hip_bfloat16 b = __float2bfloat16(f);
    return *(ushort_t*)&b;
}

// ---------------------------------------------------------------------------
// Merged split kernel: one dispatch does all three fp32->bf16(hi,lo) splits.
//   seg 0 (blocks    0..1535): x        -> Ah, Al      (row-major, float4)
//   seg 1 (blocks 1536..3263): w_qkv    -> BhT, BlT    (transposed)
//   seg 2 (blocks 3264..3839): w_proj   -> PhT, PlT    (transposed)
// Outputs bitwise identical to the previous three kernels.
// ---------------------------------------------------------------------------
__global__ __launch_bounds__(256) void split_all(const float* __restrict__ x,
                                                 ushort_t* __restrict__ hi,
                                                 ushort_t* __restrict__ lo,
                                                 const float* __restrict__ wq,
                                                 ushort_t* __restrict__ qhiT,
                                                 ushort_t* __restrict__ qloT,
                                                 const float* __restrict__ wp,
                                                 ushort_t* __restrict__ phiT,
                                                 ushort_t* __restrict__ ploT)
{
    const int bidx = blockIdx.x;
    if (bidx < 1536) {                       // x: 1536*256 float4s exactly
        const int i = bidx * 256 + threadIdx.x;
        const float4 v = ((const float4*)x)[i];
        const float f[4] = {v.x, v.y, v.z, v.w};
        ushort_t hb[4], lb[4];
        #pragma unroll
        for (int j = 0; j < 4; ++j) {
            __hip_bfloat16 h = __float2bfloat16(f[j]);
            __hip_bfloat16 l = __float2bfloat16(f[j] - __bfloat162float(h));
            hb[j] = *(ushort_t*)&h;
            lb[j] = *(ushort_t*)&l;
        }
        *(ushort4*)(hi + i * 4) = make_ushort4(hb[0], hb[1], hb[2], hb[3]);
        *(ushort4*)(lo + i * 4) = make_ushort4(lb[0], lb[1], lb[2], lb[3]);
    } else if (bidx < 3264) {                // w_qkv: 384x1152, 1728*256 elems exactly
        const int idx = (bidx - 1536) * 256 + threadIdx.x;
        const int k = idx / C3;
        const int n = idx - k * C3;
        const float v = wq[idx];
        __hip_bfloat16 h = __float2bfloat16(v);
        __hip_bfloat16 l = __float2bfloat16(v - __bfloat162float(h));
        qhiT[n * C_DIM + k] = *(ushort_t*)&h;
        qloT[n * C_DIM + k] = *(ushort_t*)&l;
    } else {                                 // w_proj: 384x384, 576*256 elems exactly
        const int idx = (bidx - 3264) * 256 + threadIdx.x;
        const int k = idx / C_DIM;
        const int n = idx - k * C_DIM;
        const float v = wp[idx];
        __hip_bfloat16 h = __float2bfloat16(v);
        __hip_bfloat16 l = __float2bfloat16(v - __bfloat162float(h));
        phiT[n * C_DIM + k] = *(ushort_t*)&h;
        ploT[n * C_DIM + k] = *(ushort_t*)&l;
    }
}

// ---------------------------------------------------------------------------
// fp32 W[K][N] -> transposed bf16 splits (fallback path only).
// ---------------------------------------------------------------------------
__global__ __launch_bounds__(256) void split_wT_kernel(const float* __restrict__ w,
                                                       ushort_t* __restrict__ hiT,
                                                       ushort_t* __restrict__ loT,
                                                       int K, int N)
{
    const int idx = blockIdx.x * 256 + threadIdx.x;
    if (idx >= K * N) return;
    const int k = idx / N;
    const int n = idx - k * N;
    const float v = w[idx];
    __hip_bfloat16 h = __float2bfloat16(v);
    __hip_bfloat16 l = __float2bfloat16(v - __bfloat162float(h));
    hiT[n * K + k] = *(ushort_t*)&h;
    loT[n * K + k] = *(ushort_t*)&l;
}

// ---------------------------------------------------------------------------
// Split-precision MFMA GEMM: C ~= AhBh + AhBl + AlBh (fp32-equivalent).
// Tile 128x64, BK=32, 4 waves.  1D grid + bijective XCD-chunked swizzle (T1):
// nwg%8==0 required (576 and 192 both qualify).  Each XCD gets a contiguous
// bm-range x all bn -> its A-panels + B fit one 4MB L2 (A fetched once/chip).
// Per-block work identical to the r16-proven kernel; only block->tile map
// changed.
// ---------------------------------------------------------------------------
__global__ __launch_bounds__(256) void gemm_mfma3(const ushort_t* __restrict__ Ah,
                                                  const ushort_t* __restrict__ Al,
                                                  const ushort_t* __restrict__ BhT,
                                                  const ushort_t* __restrict__ BlT,
                                                  const float* __restrict__ bias,
                                                  float* __restrict__ C,
                                                  int N, int K, int gn)
{
    __shared__ ushort_t sAh[128 * 40];
    __shared__ ushort_t sAl[128 * 40];
    __shared__ ushort_t sBh[64 * 40];
    __shared__ ushort_t sBl[64 * 40];

    const int tid = threadIdx.x;
    // XCD-chunked bijective swizzle (nwg % 8 == 0)
    const int nwg = gridDim.x;
    const int orig = blockIdx.x;
    const int wg = (orig & 7) * (nwg >> 3) + (orig >> 3);
    const int bmi = wg / gn;
    const int bni = wg - bmi * gn;
    const int bm = bmi * 128;
    const int bn = bni * 64;

    const int rowA = tid >> 2;
    const int slotA = (tid & 3) * 8;
    const int rowB = tid >> 2;
    const int slotB = (tid & 3) * 8;

    const ushort_t* gAh0 = Ah + (size_t)(bm + rowA) * K + slotA;
    const ushort_t* gAh1 = Ah + (size_t)(bm + rowA + 64) * K + slotA;
    const ushort_t* gAl0 = Al + (size_t)(bm + rowA) * K + slotA;
    const ushort_t* gAl1 = Al + (size_t)(bm + rowA + 64) * K + slotA;
    const ushort_t* gBh  = BhT + (size_t)(bn + rowB) * K + slotB;
    const ushort_t* gBl  = BlT + (size_t)(bn + rowB) * K + slotB;

    const int lane = tid & 63;
    const int wid = tid >> 6;
    const int wm = wid >> 1;
    const int wn = wid & 1;
    const int fr = lane & 15;
    const int kb = lane >> 4;
    const int aoff = (wm * 64 + fr) * 40 + kb * 8;
    const int boff = (wn * 32 + fr) * 40 + kb * 8;

    f32x4 acc[4][2] = {};

    for (int k0 = 0; k0 < K; k0 += 32) {
        const short8 va0 = *(const short8*)(gAh0 + k0);
        const short8 va1 = *(const short8*)(gAh1 + k0);
        const short8 vl0 = *(const short8*)(gAl0 + k0);
        const short8 vl1 = *(const short8*)(gAl1 + k0);
        const short8 vb0 = *(const short8*)(gBh + k0);
        const short8 vb1 = *(const short8*)(gBl + k0);
        *(short8*)&sAh[rowA * 40 + slotA]        = va0;
        *(short8*)&sAh[(rowA + 64) * 40 + slotA] = va1;
        *(short8*)&sAl[rowA * 40 + slotA]        = vl0;
        *(short8*)&sAl[(rowA + 64) * 40 + slotA] = vl1;
        *(short8*)&sBh[rowB * 40 + slotB]        = vb0;
        *(short8*)&sBl[rowB * 40 + slotB]        = vb1;
        __syncthreads();

        short8 ah[4], al[4], bh[2], bl[2];
        #pragma unroll
        for (int m = 0; m < 4; ++m) {
            ah[m] = *(const short8*)&sAh[aoff + m * 16 * 40];
            al[m] = *(const short8*)&sAl[aoff + m * 16 * 40];
        }
        #pragma unroll
        for (int n = 0; n < 2; ++n) {
            bh[n] = *(const short8*)&sBh[boff + n * 16 * 40];
            bl[n] = *(const short8*)&sBl[boff + n * 16 * 40];
        }
        #pragma unroll
        for (int m = 0; m < 4; ++m) {
            #pragma unroll
            for (int n = 0; n < 2; ++n) {
                acc[m][n] = __builtin_amdgcn_mfma_f32_16x16x32_bf16(ah[m], bh[n], acc[m][n], 0, 0, 0);
                acc[m][n] = __builtin_amdgcn_mfma_f32_16x16x32_bf16(ah[m], bl[n], acc[m][n], 0, 0, 0);
                acc[m][n] = __builtin_amdgcn_mfma_f32_16x16x32_bf16(al[m], bh[n], acc[m][n], 0, 0, 0);
            }
        }
        __syncthreads();
    }

    #pragma unroll
    for (int n = 0; n < 2; ++n) {
        const int col = bn + wn * 32 + n * 16 + fr;
        const float bv = bias ? bias[col] : 0.f;
        #pragma unroll
        for (int m = 0; m < 4; ++m) {
            const int r0 = bm + wm * 64 + m * 16 + kb * 4;
            #pragma unroll
            for (int r = 0; r < 4; ++r) {
                C[(size_t)(r0 + r) * N + col] = acc[m][n][r] + bv;
            }
        }
    }
}

// ---------------------------------------------------------------------------
// fp32 fallback GEMM (only if ws too small for MFMA path).
// ---------------------------------------------------------------------------
__global__ __launch_bounds__(256) void gemm64(const float* __restrict__ A,
                                              const float* __restrict__ B,
                                              const float* __restrict__ bias,
                                              float* __restrict__ C,
                                              int M, int N, int K)
{
    __shared__ float As[64][17];
    __shared__ float Bs[16][64];

    const int tid = threadIdx.x;
    const int tx = tid & 15;
    const int ty = tid >> 4;
    const int bm = blockIdx.x * 64;
    const int bn = blockIdx.y * 64;
    const int arow = tid >> 2;
    const int acol = (tid & 3) << 2;
    const int brow = tid >> 4;
    const int bcol = (tid & 15) << 2;

    float acc[4][4] = {};

    for (int k0 = 0; k0 < K; k0 += 16) {
        const float4 a4 = *(const float4*)(A + (size_t)(bm + arow) * K + k0 + acol);
        const float4 b4 = *(const float4*)(B + (size_t)(k0 + brow) * N + bn + bcol);
        As[arow][acol + 0] = a4.x; As[arow][acol + 1] = a4.y;
        As[arow][acol + 2] = a4.z; As[arow][acol + 3] = a4.w;
        *(float4*)&Bs[brow][bcol] = b4;
        __syncthreads();
        #pragma unroll
        for (int kk = 0; kk < 16; ++kk) {
            const float a0 = As[ty * 4 + 0][kk];
            const float a1 = As[ty * 4 + 1][kk];
            const float a2 = As[ty * 4 + 2][kk];
            const float a3 = As[ty * 4 + 3][kk];
            const float4 b = *(const float4*)&Bs[kk][tx * 4];
            acc[0][0] = fmaf(a0, b.x, acc[0][0]); acc[0][1] = fmaf(a0, b.y, acc[0][1]);
            acc[0][2] = fmaf(a0, b.z, acc[0][2]); acc[0][3] = fmaf(a0, b.w, acc[0][3]);
            acc[1][0] = fmaf(a1, b.x, acc[1][0]); acc[1][1] = fmaf(a1, b.y, acc[1][1]);
            acc[1][2] = fmaf(a1, b.z, acc[1][2]); acc[1][3] = fmaf(a1, b.w, acc[1][3]);
            acc[2][0] = fmaf(a2, b.x, acc[2][0]); acc[2][1] = fmaf(a2, b.y, acc[2][1]);
            acc[2][2] = fmaf(a2, b.z, acc[2][2]); acc[2][3] = fmaf(a2, b.w, acc[2][3]);
            acc[3][0] = fmaf(a3, b.x, acc[3][0]); acc[3][1] = fmaf(a3, b.y, acc[3][1]);
            acc[3][2] = fmaf(a3, b.z, acc[3][2]); acc[3][3] = fmaf(a3, b.w, acc[3][3]);
        }
        __syncthreads();
    }

    float4 bb = {0.f, 0.f, 0.f, 0.f};
    if (bias) bb = *(const float4*)(bias + bn + tx * 4);
    #pragma unroll
    for (int i = 0; i < 4; ++i) {
        float4 o;
        o.x = acc[i][0] + bb.x; o.y = acc[i][1] + bb.y;
        o.z = acc[i][2] + bb.z; o.w = acc[i][3] + bb.w;
        *(float4*)(C + (size_t)(bm + ty * 4 + i) * N + bn + tx * 4) = o;
    }
}

// ---------------------------------------------------------------------------
// MFMA local attention v5 (r19-measured; unchanged).
// ---------------------------------------------------------------------------
#define KP_SHORTS 18432   // K: 280 rows*64 = 17920 staged + 512 pad; P: 7*32*72 = 16128
#define PROW 72
__global__ __launch_bounds__(512) void local_attn_mfma5(const float* __restrict__ qkv,
                                                        ushort_t* __restrict__ outHi,
                                                        ushort_t* __restrict__ outLo)
{
    __shared__ ushort_t sKP[KP_SHORTS];     // 36864 B
    __shared__ ushort_t sV[13504];          // 27008 B (13440 staged + 64 pad)
    __shared__ ushort_t sQ[2048];           //  4096 B (32 q x 64 d, swizzled)
    __shared__ float    sS[32 * 57];        //  7296 B (57 coprime 32 -> bank-clean)

    const int tid = threadIdx.x;
    const int b = blockIdx.x;
    const int t = b >> 8, h = (b >> 3) & 31, head = b & 7;

    // ---- zero ONLY the frag-overrun pads (NaN-safety; 0 x NaN = NaN) ----
    if (tid < 288) {
        if (tid < 256) ((unsigned int*)(sKP + 17920))[tid] = 0u;
        else           ((unsigned int*)(sV + 13440))[tid - 256] = 0u;
    }

    // ---- phase 1: stage Q + K only (float2 loads, packed stores) ----
    #pragma unroll
    for (int it = 0; it < 2; ++it) {
        const int i = tid + it * 512;
        const int q = i >> 5, d = (i & 31) * 2;
        float2 v = make_float2(0.f, 0.f);
        if (d < 48)
            v = *(const float2*)(qkv + (size_t)((t << 10) + (h << 5) + q) * C3 + head * HD + d);
        const unsigned int pk = (unsigned int)bf16u(v.x * SCALE_F) | ((unsigned int)bf16u(v.y * SCALE_F) << 16);
        *(unsigned int*)&sQ[q * 64 + (d ^ ((q & 7) << 3))] = pk;
    }
    #pragma unroll
    for (int r = 0; r < 7; ++r) {
        const int hk = h + r - 3;
        const bool rowok = (unsigned)hk < 32u;
        const size_t rk = (size_t)((t << 10) + (hk << 5)) * C3 + C_DIM + head * HD;
        for (int i = tid; i < 1280; i += 512) {
            const int slot = i >> 5, d = (i & 31) * 2;
            const int c = slot - 3;
            float2 v = make_float2(0.f, 0.f);
            if (rowok && (unsigned)c < 32u && d < 48)
                v = *(const float2*)(qkv + rk + (size_t)c * C3 + d);
            const unsigned int pk = (unsigned int)bf16u(v.x) | ((unsigned int)bf16u(v.y) << 16);
            *(unsigned int*)&sKP[(r * 40 + slot) * 64 + (d ^ ((slot & 7) << 3))] = pk;
        }
    }
    __syncthreads();

    const int wv = tid >> 6, l = tid & 63, lr = l & 15, lc = l >> 4;

    // ---- phase 2: ISSUE V loads to regs, then scores (loads fly under MFMA) ----
    float2 vreg[7][2];
    #pragma unroll
    for (int r = 0; r < 7; ++r) {
        const int hk = h + r - 3;
        const bool rowok = (unsigned)hk < 32u;
        const size_t rv = (size_t)((t << 10) + (hk << 5)) * C3 + 2 * C_DIM + head * HD;
        #pragma unroll
        for (int it = 0; it < 2; ++it) {
            const int i = tid + it * 512;
            float2 v = make_float2(0.f, 0.f);
            if (i < 960) {
                const int slot = i / 24;
                const int d = (i - slot * 24) * 2;
                const int c = slot - 3;
                if (rowok && (unsigned)c < 32u)
                    v = *(const float2*)(qkv + rv + (size_t)c * C3 + d);
            }
            vreg[r][it] = v;
        }
    }
    {
        short8 aq[2][2];
        #pragma unroll
        for (int fm = 0; fm < 2; ++fm) {
            const int q = fm * 16 + lr;
            aq[fm][0] = *(const short8*)&sQ[q * 64 + ((lc * 8) ^ ((q & 7) << 3))];
            aq[fm][1] = *(const short8*)&sQ[q * 64 + ((lc * 8 + 32) ^ ((q & 7) << 3))];
        }
        for (int u = wv; u < 21; u += 8) {
            const int r = u / 3, fn = u - r * 3;
            const int slot = fn * 16 + lr;
            const short8 b0 = *(const short8*)&sKP[(r * 40 + slot) * 64 + ((lc * 8) ^ ((slot & 7) << 3))];
            const short8 b1 = *(const short8*)&sKP[(r * 40 + slot) * 64 + ((lc * 8 + 32) ^ ((slot & 7) << 3))];
            f32x4 acc0 = {}, acc1 = {};
            acc0 = __builtin_amdgcn_mfma_f32_16x16x32_bf16(aq[0][0], b0, acc0, 0, 0, 0);
            acc0 = __builtin_amdgcn_mfma_f32_16x16x32_bf16(aq[0][1], b1, acc0, 0, 0, 0);
            acc1 = __builtin_amdgcn_mfma_f32_16x16x32_bf16(aq[1][0], b0, acc1, 0, 0, 0);
            acc1 = __builtin_amdgcn_mfma_f32_16x16x32_bf16(aq[1][1], b1, acc1, 0, 0, 0);
            // banded scatter: keep C elem (q, slot) iff 0 <= slot - q <= 6
            #pragma unroll
            for (int reg = 0; reg < 4; ++reg) {
                const int q0 = lc * 4 + reg;
                const int dx0 = slot - q0;
                if (dx0 >= 0 && dx0 < 7) sS[q0 * 57 + r * 7 + dx0] = acc0[reg];
                const int q1 = 16 + lc * 4 + reg;
                const int dx1 = slot - q1;
                if (dx1 >= 0 && dx1 < 7) sS[q1 * 57 + r * 7 + dx1] = acc1[reg];
            }
        }
    }
    __syncthreads();

    // ---- phase 3: V cvt+store (all) + softmax (0..31) || zero-P (32..511) ----
    #pragma unroll
    for (int r = 0; r < 7; ++r) {
        #pragma unroll
        for (int it = 0; it < 2; ++it) {
            const int i = tid + it * 512;
            if (i < 960) {
                const int slot = i / 24;
                const int d = (i - slot * 24) * 2;
                sV[(r * 48 + d) * 40 + slot]     = bf16u(vreg[r][it].x);
                sV[(r * 48 + d + 1) * 40 + slot] = bf16u(vreg[r][it].y);
            }
        }
    }
    if (tid < 32) {
        const int q = tid;
        float sv[49];
        #pragma unroll
        for (int j = 0; j < 49; ++j) sv[j] = sS[q * 57 + j];
        float mx = sv[0];
        #pragma unroll
        for (int j = 1; j < 49; ++j) mx = fmaxf(mx, sv[j]);
        float sum = 0.f;
        #pragma unroll
        for (int j = 0; j < 49; ++j) { sv[j] = __expf(sv[j] - mx); sum += sv[j]; }
        const float inv = 1.f / sum;   // zero-padded keys in denominator (ref semantics)
        #pragma unroll
        for (int j = 0; j < 49; ++j) {
            const int r = j / 7, dx = j - (j / 7) * 7;
            sKP[(r * 32 + q) * PROW + q + dx] = bf16u(sv[j] * inv);
        }
    } else {
        for (int i = tid - 32; i < 7 * 32 * PROW; i += 480) {
            const int row = i / PROW;
            const int col = i - row * PROW;
            const int q = row & 31;
            if ((unsigned)(col - q) >= 7u)     // skip softmax band
                sKP[i] = 0;
        }
    }
    __syncthreads();

    // ---- phase 4: PV (waves 0..5 own (fm, fn) tiles) + fused hi/lo split ----
    if (wv < 6) {
        const int fm = (wv >= 3) ? 1 : 0;
        const int fn = wv - fm * 3;
        const int q = fm * 16 + lr;
        const int dim = fn * 16 + lr;
        f32x4 acc = {};
        #pragma unroll
        for (int r = 0; r < 7; ++r) {
            const short8 a0 = *(const short8*)&sKP[(r * 32 + q) * PROW + lc * 8];
            const short8 a1 = *(const short8*)&sKP[(r * 32 + q) * PROW + lc * 8 + 32];
            const short8 b0 = *(const short8*)&sV[(r * 48 + dim) * 40 + lc * 8];
            const short8 b1 = *(const short8*)&sV[(r * 48 + dim) * 40 + lc * 8 + 32];
            acc = __builtin_amdgcn_mfma_f32_16x16x32_bf16(a0, b0, acc, 0, 0, 0);
            acc = __builtin_amdgcn_mfma_f32_16x16x32_bf16(a1, b1, acc, 0, 0, 0);
        }
        #pragma unroll
        for (int reg = 0; reg < 4; ++reg) {
            const int qq = fm * 16 + lc * 4 + reg;
            const int n = (t << 10) | (h << 5) | qq;
            const float o = acc[reg];
            __hip_bfloat16 hb = __float2bfloat16(o);
            __hip_bfloat16 lb = __float2bfloat16(o - __bfloat162float(hb));
            const size_t ob = (size_t)n * C_DIM + head * HD + dim;
            outHi[ob] = *(ushort_t*)&hb;
            outLo[ob] = *(ushort_t*)&lb;
        }
    }
}

// ---------------------------------------------------------------------------
// fp32 fallback attention (only if ws too small for MFMA path).
// ---------------------------------------------------------------------------
__global__ __launch_bounds__(256) void local_attn16(const float* __restrict__ qkv,
                                                    float* __restrict__ out)
{
    const int tid = threadIdx.x;
    const int dlane = tid & 15;
    const int gid = blockIdx.x * 16 + (tid >> 4);
    const int head = gid & 7;
    const int n = gid >> 3;
    const int t = n >> 10;
    const int h = (n >> 5) & 31;
    const int w = n & 31;
    const float scale = SCALE_F;

    const float* qp = qkv + (size_t)n * C3 + head * HD;
    const float q0 = qp[dlane];
    const float q1 = qp[dlane + 16];
    const float q2 = qp[dlane + 32];

    const size_t base_k = (size_t)(C_DIM + head * HD);
    const size_t base_v = (size_t)(2 * C_DIM + head * HD);

    float s[49];
    #pragma unroll
    for (int p = 0; p < 49; ++p) {
        const int dy = p / 7, dx = p % 7;
        const int hk = h + dy - 3;
        const int wk = w + dx - 3;
        float sc = 0.f;
        if ((unsigned)hk < 32u && (unsigned)wk < 32u) {
            const int nk = (t << 10) | (hk << 5) | wk;
            const float* kp = qkv + (size_t)nk * C3 + base_k;
            float acc = q0 * kp[dlane];
            acc = fmaf(q1, kp[dlane + 16], acc);
            acc = fmaf(q2, kp[dlane + 32], acc);
            acc += __shfl_xor(acc, 1, 16);
            acc += __shfl_xor(acc, 2, 16);
            acc += __shfl_xor(acc, 4, 16);
            acc += __shfl_xor(acc, 8, 16);
            sc = acc * scale;
        }
        s[p] = sc;
    }

    float m = s[0];
    #pragma unroll
    for (int p = 1; p < 49; ++p) m = fmaxf(m, s[p]);
    float sum = 0.f;
    #pragma unroll
    for (int p = 0; p < 49; ++p) { s[p] = __expf(s[p] - m); sum += s[p]; }
    const float inv = 1.f / sum;

    float o0 = 0.f, o1 = 0.f, o2 = 0.f;
    #pragma unroll
    for (int p = 0; p < 49; ++p) {
        const int dy = p / 7, dx = p % 7;
        const int hk = h + dy - 3;
        const int wk = w + dx - 3;
        if ((unsigned)hk < 32u && (unsigned)wk < 32u) {
            const float wgt = s[p] * inv;
            const int nk = (t << 10) | (hk << 5) | wk;
            const float* vp = qkv + (size_t)nk * C3 + base_v;
            o0 = fmaf(wgt, vp[dlane],      o0);
            o1 = fmaf(wgt, vp[dlane + 16], o1);
            o2 = fmaf(wgt, vp[dlane + 32], o2);
        }
    }

    float* op = out + (size_t)n * C_DIM + head * HD;
    op[dlane]      = o0;
    op[dlane + 16] = o1;
    op[dlane + 32] = o2;
}

extern "C" void kernel_launch(void* const* d_in, const int* in_sizes, int n_in,
                              void* d_out, int out_size, void* d_ws, size_t ws_size,
                              hipStream_t stream)
{
    const float* x      = (const float*)d_in[0];
    const float* w_qkv  = (const float*)d_in[1];
    const float* w_proj = (const float*)d_in[2];
    const float* b_proj = (const float*)d_in[3];

    const int M = 4096;
    dim3 blk(256);

    // ws layout (bytes):
    //   qkv fp32   [4096x1152] @ 0         (18,874,368)
    //   att fp32   [4096x384]  @ 18874368  ( 6,291,456)  (fallback only)
    //   Ah  bf16   [4096x384]  @ 25165824  ( 3,145,728)
    //   Al  bf16   [4096x384]  @ 28311552  ( 3,145,728)
    //   BhT bf16   [1152x384]  @ 31457280  (   884,736)   qkv weights
    //   BlT bf16   [1152x384]  @ 32342016  (   884,736)
    //   PhT bf16   [384x384]   @ 33226752  (   294,912)   proj weights
    //   PlT bf16   [384x384]   @ 33521664  (   294,912)
    const size_t NEED = 33816576;

    unsigned char* ws = (unsigned char*)d_ws;
    float* qkv = (float*)ws;
    float* att = (float*)(ws + 18874368);

    if (ws_size >= NEED) {
        ushort_t* Ah  = (ushort_t*)(ws + 25165824);
        ushort_t* Al  = (ushort_t*)(ws + 28311552);
        ushort_t* BhT = (ushort_t*)(ws + 31457280);
        ushort_t* BlT = (ushort_t*)(ws + 32342016);
        ushort_t* PhT = (ushort_t*)(ws + 33226752);
        ushort_t* PlT = (ushort_t*)(ws + 33521664);

        // one dispatch: x-split + both transposed weight splits
        split_all<<<dim3(3840), blk, 0, stream>>>(x, Ah, Al, w_qkv, BhT, BlT, w_proj, PhT, PlT);

        // QKV GEMM: 1D grid 576, XCD-chunked swizzle, gn=18
        gemm_mfma3<<<dim3(576), blk, 0, stream>>>(Ah, Al, BhT, BlT, nullptr, qkv, C3, C_DIM, 18);

        // MFMA attention v5: writes bf16 hi/lo split directly (overwrites Ah/Al)
        local_attn_mfma5<<<dim3(1024), dim3(512), 0, stream>>>(qkv, Ah, Al);

        // proj GEMM: 1D grid 192, swizzle, gn=6
        gemm_mfma3<<<dim3(192), blk, 0, stream>>>(Ah, Al, PhT, PlT, b_proj, (float*)d_out, C_DIM, C_DIM, 6);
    } else {
        gemm64<<<dim3(M / 64, C3 / 64), blk, 0, stream>>>(x, w_qkv, nullptr, qkv, M, C3, C_DIM);
        local_attn16<<<dim3(2048), blk, 0, stream>>>(qkv, att);
        gemm64<<<dim3(M / 64, C_DIM / 64), blk, 0, stream>>>(att, w_proj, b_proj, (float*)d_out, M, C_DIM, C_DIM);
    }
}